// Round 2
// baseline (571.225 us; speedup 1.0000x reference)
//
#include <hip/hip_runtime.h>
#include <hip/hip_bf16.h>

typedef __attribute__((ext_vector_type(8))) short short8;
typedef __attribute__((ext_vector_type(4))) float f32x4;

#define S_TOK 2048
#define QKV_LD 6144

__device__ __forceinline__ ushort f2b(float f) {
  __hip_bfloat16 h = __float2bfloat16(f);
  union { __hip_bfloat16 h; ushort u; } v; v.h = h; return v.u;
}

__device__ __forceinline__ void async_load16(const void* g, void* l) {
  __builtin_amdgcn_global_load_lds(
      (const __attribute__((address_space(1))) unsigned int*)g,
      (__attribute__((address_space(3))) unsigned int*)l, 16, 0, 0);
}

// fp32 -> bf16 convert (RNE), float4 vectorized
__global__ __launch_bounds__(256) void cvt_f32_bf16(const float* __restrict__ in,
                                                    ushort* __restrict__ out, int n) {
  int i = (blockIdx.x * 256 + threadIdx.x) * 4;
  if (i < n) {
    float4 v = *(const float4*)(in + i);
    ushort4 o;
    o.x = f2b(v.x); o.y = f2b(v.y); o.z = f2b(v.z); o.w = f2b(v.w);
    *(ushort4*)(out + i) = o;
  }
}

// C = A[M,K] * B[N,K]^T, bf16 in, fp32 accum, OUTF32 selects output type.
// Tile 128x128, BK=32. LDS chunk-swizzle: slot s holds global chunk
// (row=s>>2, kofs=((s&3)^((row>>1)&3))*8) so frag ds_read_b128 at (row,quad)
// -> slot row*4+(quad^((row>>1)&3)) : 2-way banks (free).
template <bool OUTF32>
__global__ __launch_bounds__(256) void gemm_bt(const ushort* __restrict__ A,
                                               const ushort* __restrict__ Bw,
                                               void* __restrict__ Cv,
                                               int lda, int ldb, int ldc) {
  __shared__ __align__(16) ushort As[128 * 32];
  __shared__ __align__(16) ushort Bs[128 * 32];
  const int tid  = threadIdx.x;
  const int lane = tid & 63;
  const int w    = tid >> 6;
  const int quad = lane >> 4;
  const int l15  = lane & 15;
  const int m0 = blockIdx.x * 128;
  const int n0 = blockIdx.y * 128;
  const int wm = (w & 1) * 64;
  const int wn = (w >> 1) * 64;

  int srow[2], skof[2], sslot[2];
  #pragma unroll
  for (int j = 0; j < 2; ++j) {
    int s = tid + j * 256;
    int row = s >> 2;
    int qp  = s & 3;
    srow[j]  = row;
    skof[j]  = (qp ^ ((row >> 1) & 3)) * 8;
    sslot[j] = s;
  }

  f32x4 acc[4][4];
  #pragma unroll
  for (int i = 0; i < 4; ++i)
    #pragma unroll
    for (int j = 0; j < 4; ++j) acc[i][j] = (f32x4){0.f, 0.f, 0.f, 0.f};

  for (int k0 = 0; k0 < 2048; k0 += 32) {
    #pragma unroll
    for (int j = 0; j < 2; ++j) {
      async_load16(A  + (size_t)(m0 + srow[j]) * lda + k0 + skof[j], &As[sslot[j] * 8]);
      async_load16(Bw + (size_t)(n0 + srow[j]) * ldb + k0 + skof[j], &Bs[sslot[j] * 8]);
    }
    __syncthreads();
    short8 af[4], bf[4];
    #pragma unroll
    for (int mi = 0; mi < 4; ++mi) {
      int row = wm + mi * 16 + l15;
      int slot = row * 4 + (quad ^ ((row >> 1) & 3));
      af[mi] = *(const short8*)&As[slot * 8];
    }
    #pragma unroll
    for (int ni = 0; ni < 4; ++ni) {
      int row = wn + ni * 16 + l15;
      int slot = row * 4 + (quad ^ ((row >> 1) & 3));
      bf[ni] = *(const short8*)&Bs[slot * 8];
    }
    #pragma unroll
    for (int mi = 0; mi < 4; ++mi)
      #pragma unroll
      for (int ni = 0; ni < 4; ++ni)
        acc[mi][ni] = __builtin_amdgcn_mfma_f32_16x16x32_bf16(af[mi], bf[ni], acc[mi][ni], 0, 0, 0);
    __syncthreads();
  }

  #pragma unroll
  for (int mi = 0; mi < 4; ++mi)
    #pragma unroll
    for (int ni = 0; ni < 4; ++ni)
      #pragma unroll
      for (int r = 0; r < 4; ++r) {
        int rr = m0 + wm + mi * 16 + quad * 4 + r;
        int cc = n0 + wn + ni * 16 + l15;
        if constexpr (OUTF32)
          ((float*)Cv)[(size_t)rr * ldc + cc] = acc[mi][ni][r];
        else
          ((ushort*)Cv)[(size_t)rr * ldc + cc] = f2b(acc[mi][ni][r]);
      }
}

// In-place RoPE on Q and K regions of QKV buffer (bf16).
__global__ __launch_bounds__(256) void rope_k(ushort* __restrict__ QKV) {
  const int t = blockIdx.x * 256 + threadIdx.x;
  const int j = t & 63;
  const int h = (t >> 6) & 15;
  const int row = t >> 10;           // 0..4095
  const int pos = row & (S_TOK - 1);
  const float invf = __expf(-0.14391156831212787f * (float)j);  // 10000^(-j/64)
  const float ph = (float)pos * invf;
  float sn, cs;
  __sincosf(ph, &sn, &cs);
  size_t base = (size_t)row * QKV_LD + h * 128 + j;
  float x1 = __bfloat162float(*(__hip_bfloat16*)&QKV[base]);
  float x2 = __bfloat162float(*(__hip_bfloat16*)&QKV[base + 64]);
  QKV[base]      = f2b(x1 * cs - x2 * sn);
  QKV[base + 64] = f2b(x1 * sn + x2 * cs);
  float y1 = __bfloat162float(*(__hip_bfloat16*)&QKV[base + 2048]);
  float y2 = __bfloat162float(*(__hip_bfloat16*)&QKV[base + 2048 + 64]);
  QKV[base + 2048]      = f2b(y1 * cs - y2 * sn);
  QKV[base + 2048 + 64] = f2b(y1 * sn + y2 * cs);
}

// Flash attention: block = (qt, h, b), 256 threads (4 waves x 32 Q-rows), KV tiles of 64.
__global__ __launch_bounds__(256) void attn_k(const ushort* __restrict__ QKV,
                                              ushort* __restrict__ Ob) {
  __shared__ __align__(16) ushort Ks[64 * 136];    // K tile, pad 136 -> 2-way banks
  __shared__ __align__(16) ushort Vts[128 * 72];   // V^T tile [hd][kv], pad 72
  __shared__ __align__(16) ushort Pb[9216];        // per-wave P [32][72]; reused as V staging [64][136]
  const int qt = blockIdx.x, h = blockIdx.y, b = blockIdx.z;
  const int q0 = qt * 128;
  const int tid = threadIdx.x, lane = tid & 63, w = tid >> 6;
  const int quad = lane >> 4, l15 = lane & 15;
  const size_t rowbase = (size_t)b * S_TOK;

  // Q fragments (A-layout: A[m=lane&15][k=quad*8+j]) straight from global
  short8 qf[2][4];
  #pragma unroll
  for (int m = 0; m < 2; ++m)
    #pragma unroll
    for (int ks = 0; ks < 4; ++ks)
      qf[m][ks] = *(const short8*)(QKV + (rowbase + q0 + w * 32 + m * 16 + l15) * QKV_LD
                                   + h * 128 + ks * 32 + quad * 8);

  f32x4 o[2][8];
  #pragma unroll
  for (int m = 0; m < 2; ++m)
    #pragma unroll
    for (int no = 0; no < 8; ++no) o[m][no] = (f32x4){0.f, 0.f, 0.f, 0.f};
  float mr[2][4], lr[2][4];
  #pragma unroll
  for (int m = 0; m < 2; ++m)
    #pragma unroll
    for (int r = 0; r < 4; ++r) { mr[m][r] = -1e30f; lr[m][r] = 0.f; }

  const int ntiles = 2 * qt + 2;   // causal: kv <= q0+127
  for (int t = 0; t < ntiles; ++t) {
    const int kv0 = t * 64;
    __syncthreads();   // prior iteration's LDS reads done
    // stage K tile and V tile (V row-major into Pb scratch)
    #pragma unroll
    for (int j = 0; j < 4; ++j) {
      int c = tid + j * 256;                 // 0..1023
      int row = c >> 4, cof = (c & 15) * 8;
      const size_t gr = (rowbase + kv0 + row) * QKV_LD + h * 128 + cof;
      *(short8*)&Ks[row * 136 + cof] = *(const short8*)(QKV + gr + 2048);
      *(short8*)&Pb[row * 136 + cof] = *(const short8*)(QKV + gr + 4096);
    }
    __syncthreads();
    // transpose V staging -> Vts[hd][kv]
    #pragma unroll
    for (int j = 0; j < 4; ++j) {
      int c = tid + j * 256;
      int hd = c & 127, kk = (c >> 7) * 8;
      short8 v;
      #pragma unroll
      for (int u = 0; u < 8; ++u) v[u] = (short)Pb[(kk + u) * 136 + hd];
      *(short8*)&Vts[hd * 72 + kk] = v;
    }
    __syncthreads();

    // S = Q K^T
    f32x4 sc[2][4];
    #pragma unroll
    for (int n = 0; n < 4; ++n) {
      short8 kf[4];
      #pragma unroll
      for (int ks = 0; ks < 4; ++ks)
        kf[ks] = *(const short8*)&Ks[(n * 16 + l15) * 136 + ks * 32 + quad * 8];
      #pragma unroll
      for (int m = 0; m < 2; ++m) {
        f32x4 z = (f32x4){0.f, 0.f, 0.f, 0.f};
        #pragma unroll
        for (int ks = 0; ks < 4; ++ks)
          z = __builtin_amdgcn_mfma_f32_16x16x32_bf16(qf[m][ks], kf[ks], z, 0, 0, 0);
        sc[m][n] = z;
      }
    }

    // online softmax + write P (bf16) to per-wave LDS
    const float scale = 0.08838834764831845f;   // 1/sqrt(128)
    ushort* P = &Pb[w * 2304];
    #pragma unroll
    for (int m = 0; m < 2; ++m) {
      const int rowg0 = q0 + w * 32 + m * 16 + quad * 4;
      #pragma unroll
      for (int r = 0; r < 4; ++r) {
        const int rowg = rowg0 + r;
        float s[4];
        #pragma unroll
        for (int n = 0; n < 4; ++n) {
          float v = sc[m][n][r] * scale;
          int col = kv0 + n * 16 + l15;
          if (col > rowg) v = -1e30f;
          s[n] = v;
        }
        float mx = fmaxf(fmaxf(s[0], s[1]), fmaxf(s[2], s[3]));
        #pragma unroll
        for (int off = 1; off < 16; off <<= 1) mx = fmaxf(mx, __shfl_xor(mx, off));
        float mnew = fmaxf(mr[m][r], mx);
        float alpha = __expf(mr[m][r] - mnew);
        mr[m][r] = mnew;
        float p[4], rs = 0.f;
        #pragma unroll
        for (int n = 0; n < 4; ++n) { p[n] = __expf(s[n] - mnew); rs += p[n]; }
        #pragma unroll
        for (int off = 1; off < 16; off <<= 1) rs += __shfl_xor(rs, off);
        lr[m][r] = lr[m][r] * alpha + rs;
        #pragma unroll
        for (int no = 0; no < 8; ++no) o[m][no][r] *= alpha;
        #pragma unroll
        for (int n = 0; n < 4; ++n)
          P[(m * 16 + quad * 4 + r) * 72 + n * 16 + l15] = f2b(p[n]);
      }
    }
    __asm__ volatile("s_waitcnt lgkmcnt(0)" ::: "memory");  // P writes visible to own wave

    // O += P V
    short8 pf[2][2];
    #pragma unroll
    for (int m = 0; m < 2; ++m)
      #pragma unroll
      for (int kst = 0; kst < 2; ++kst)
        pf[m][kst] = *(const short8*)&P[(m * 16 + l15) * 72 + kst * 32 + quad * 8];
    #pragma unroll
    for (int no = 0; no < 8; ++no) {
      short8 vf0 = *(const short8*)&Vts[(no * 16 + l15) * 72 + quad * 8];
      short8 vf1 = *(const short8*)&Vts[(no * 16 + l15) * 72 + 32 + quad * 8];
      #pragma unroll
      for (int m = 0; m < 2; ++m) {
        o[m][no] = __builtin_amdgcn_mfma_f32_16x16x32_bf16(pf[m][0], vf0, o[m][no], 0, 0, 0);
        o[m][no] = __builtin_amdgcn_mfma_f32_16x16x32_bf16(pf[m][1], vf1, o[m][no], 0, 0, 0);
      }
    }
  }

  // epilogue: O / l -> Ob (bf16, [4096][2048])
  #pragma unroll
  for (int m = 0; m < 2; ++m)
    #pragma unroll
    for (int no = 0; no < 8; ++no)
      #pragma unroll
      for (int r = 0; r < 4; ++r) {
        float v = o[m][no][r] / lr[m][r];
        size_t rr = rowbase + q0 + w * 32 + m * 16 + quad * 4 + r;
        Ob[rr * 2048 + h * 128 + no * 16 + l15] = f2b(v);
      }
}

extern "C" void kernel_launch(void* const* d_in, const int* in_sizes, int n_in,
                              void* d_out, int out_size, void* d_ws, size_t ws_size,
                              hipStream_t stream) {
  const float* x  = (const float*)d_in[0];
  // d_in[1] = mask (int32 causal tril) — causality is hardcoded
  const float* Wq = (const float*)d_in[2];
  const float* Wk = (const float*)d_in[3];
  const float* Wv = (const float*)d_in[4];
  const float* Wo = (const float*)d_in[5];
  float* out = (float*)d_out;

  // workspace layout (bf16 elements):
  //   xb  [4096*2048]           16.8 MB   (aliased by Ob after projections)
  //   Wb  [4][2048*2048]        33.6 MB   (q,k,v,o)
  //   QKV [4096*6144]           50.3 MB
  ushort* xb  = (ushort*)d_ws;
  ushort* Wb  = xb + (size_t)4096 * 2048;
  ushort* QKV = Wb + (size_t)4 * 2048 * 2048;
  ushort* Ob  = xb;   // x dead after projections

  const int NX = 4096 * 2048;      // 8,388,608
  const int NW = 2048 * 2048;      // 4,194,304
  dim3 blk(256);

  cvt_f32_bf16<<<dim3(NX / 1024), blk, 0, stream>>>(x,  xb, NX);
  cvt_f32_bf16<<<dim3(NW / 1024), blk, 0, stream>>>(Wq, Wb + (size_t)0 * NW, NW);
  cvt_f32_bf16<<<dim3(NW / 1024), blk, 0, stream>>>(Wk, Wb + (size_t)1 * NW, NW);
  cvt_f32_bf16<<<dim3(NW / 1024), blk, 0, stream>>>(Wv, Wb + (size_t)2 * NW, NW);
  cvt_f32_bf16<<<dim3(NW / 1024), blk, 0, stream>>>(Wo, Wb + (size_t)3 * NW, NW);

  gemm_bt<false><<<dim3(32, 16), blk, 0, stream>>>(xb, Wb + (size_t)0 * NW, QKV + 0,    2048, 2048, QKV_LD);
  gemm_bt<false><<<dim3(32, 16), blk, 0, stream>>>(xb, Wb + (size_t)1 * NW, QKV + 2048, 2048, 2048, QKV_LD);
  gemm_bt<false><<<dim3(32, 16), blk, 0, stream>>>(xb, Wb + (size_t)2 * NW, QKV + 4096, 2048, 2048, QKV_LD);
  rope_k<<<dim3(16384), blk, 0, stream>>>(QKV);
  attn_k<<<dim3(16, 16, 2), blk, 0, stream>>>(QKV, Ob);
  gemm_bt<true><<<dim3(32, 16), blk, 0, stream>>>(Ob, Wb + (size_t)3 * NW, out, 2048, 2048, 2048);
}